// Round 2
// 434.740 us; speedup vs baseline: 1.0229x; 1.0229x over previous
//
#include <hip/hip_runtime.h>

// KWinnersTakeAll: x (B=4096, D=16384) fp32. k_active = 820.
// threshold = (topv[819] + topv[820]) * 0.5 (descending top-k), mask = x > thr.
// v3: register-resident row, BLOCK=1024 / 16 floats per thread (16 data VGPRs)
// so the 64-VGPR / 8-waves-per-EU occupancy bin is met without spill risk.
// 2 blocks/CU = 32 waves/CU (full occupancy). LDS = hist + cand ~8.5 KB only.
// One block per row; 1024-bin histogram selection; exact candidate ranking;
// bitwise radix-select fallback (over registers) for pathological rows.

#define DDIM   16384
#define BLOCK  1024
#define VPT    4            // float4 per thread = 16 floats
#define NBINS  1024
#define CAP    1024
#define R1     819u
#define R2     820u

__device__ __forceinline__ unsigned f2k(float f) {
    unsigned u = __float_as_uint(f);
    return u ^ ((unsigned)((int)u >> 31) | 0x80000000u);
}
__device__ __forceinline__ float k2f(unsigned k) {
    unsigned u = (k & 0x80000000u) ? (k ^ 0x80000000u) : ~k;
    return __uint_as_float(u);
}
__device__ __forceinline__ int val2bin(float x) {
    // bin = floor((x + 8) * 64), clamped to [0, 1023]. Monotone in x.
    float t = floorf(fmaf(x, 64.0f, 512.0f));
    t = fminf(fmaxf(t, 0.0f), 1023.0f);
    return (int)t;
}

__global__ __launch_bounds__(BLOCK, 8)
void kwta_kernel(const float* __restrict__ x, float* __restrict__ out) {
    __shared__ unsigned hist[NBINS];                 // 4 KB
    __shared__ float cand[CAP];                      // 4 KB
    __shared__ unsigned s_candCount;
    __shared__ int s_b1, s_b2;
    __shared__ unsigned s_above;
    __shared__ float s_v1, s_v2;
    __shared__ unsigned s_redc[BLOCK / 64];
    __shared__ unsigned s_redm[BLOCK / 64];
    __shared__ unsigned s_total;

    const int tid = threadIdx.x;
    const size_t base = (size_t)blockIdx.x * DDIM;
    const float4* __restrict__ x4 = (const float4*)(x + base);
    float4* __restrict__ o4 = (float4*)(out + base);

    hist[tid] = 0u;                                  // NBINS == BLOCK
    if (tid == 0) s_candCount = 0u;

    // ---- Load row into registers (coalesced, 16B/lane) ----
    float4 d[VPT];
#pragma unroll
    for (int j = 0; j < VPT; ++j) d[j] = x4[j * BLOCK + tid];

    __syncthreads();   // hist cleared

    // ---- Pass A: histogram from registers ----
#pragma unroll
    for (int j = 0; j < VPT; ++j) {
        atomicAdd(&hist[val2bin(d[j].x)], 1u);
        atomicAdd(&hist[val2bin(d[j].y)], 1u);
        atomicAdd(&hist[val2bin(d[j].z)], 1u);
        atomicAdd(&hist[val2bin(d[j].w)], 1u);
    }
    __syncthreads();

    // ---- Locate bins holding descending ranks R1, R2 (wave 0 only) ----
    if (tid < 64) {
        int c = tid;
        int top = (NBINS - 1) - (c << 4);   // chunk covers bins [top-15, top]
        unsigned s = 0;
#pragma unroll
        for (int i = 0; i < 16; ++i) s += hist[top - i];
        unsigned v = s;
#pragma unroll
        for (int dd = 1; dd < 64; dd <<= 1) {
            unsigned u = __shfl_up(v, dd, 64);
            if (c >= dd) v += u;
        }
        unsigned cum = v - s;               // elements in all chunks above this one
#pragma unroll
        for (int i = 0; i < 16; ++i) {
            unsigned h = hist[top - i];
            if (R1 >= cum && R1 < cum + h) { s_b1 = top - i; s_above = cum; }
            if (R2 >= cum && R2 < cum + h) { s_b2 = top - i; }
            cum += h;
        }
    }
    __syncthreads();

    const int b1 = s_b1, b2 = s_b2;
    const unsigned above = s_above;

    // ---- Pass B: compact candidates from bins [b2, b1] (from registers) ----
#pragma unroll
    for (int j = 0; j < VPT; ++j) {
        float vals[4] = {d[j].x, d[j].y, d[j].z, d[j].w};
#pragma unroll
        for (int q = 0; q < 4; ++q) {
            int b = val2bin(vals[q]);
            if (b >= b2 && b <= b1) {
                unsigned p = atomicAdd(&s_candCount, 1u);
                if (p < CAP) cand[p] = vals[q];
            }
        }
    }
    __syncthreads();

    const unsigned C = s_candCount;
    if (C <= CAP) {
        // ---- Exact ranking among candidates ----
        for (unsigned j = tid; j < C; j += BLOCK) {
            float xj = cand[j];
            unsigned g = 0, e = 0;
            for (unsigned i = 0; i < C; ++i) {
                float xi = cand[i];
                g += (xi > xj) ? 1u : 0u;
                e += (xi == xj) ? 1u : 0u;
            }
            unsigned lo = above + g, hi = lo + e;
            if (R1 >= lo && R1 < hi) s_v1 = xj;
            if (R2 >= lo && R2 < hi) s_v2 = xj;
        }
    } else {
        // ---- Fallback: exact bitwise radix select over sortable keys (regs) ----
        unsigned prefix = 0, r = R1;
        for (int bit = 31; bit >= 0; --bit) {
            unsigned hiMask = (bit == 31) ? 0u : ~((1u << (bit + 1)) - 1u);
            unsigned bitMask = 1u << bit;
            unsigned cnt = 0;
#pragma unroll
            for (int j = 0; j < VPT; ++j) {
                unsigned k0 = f2k(d[j].x), k1 = f2k(d[j].y);
                unsigned k2 = f2k(d[j].z), k3 = f2k(d[j].w);
                cnt += (((k0 & hiMask) == prefix) && (k0 & bitMask)) ? 1u : 0u;
                cnt += (((k1 & hiMask) == prefix) && (k1 & bitMask)) ? 1u : 0u;
                cnt += (((k2 & hiMask) == prefix) && (k2 & bitMask)) ? 1u : 0u;
                cnt += (((k3 & hiMask) == prefix) && (k3 & bitMask)) ? 1u : 0u;
            }
#pragma unroll
            for (int dd = 32; dd >= 1; dd >>= 1) cnt += __shfl_xor(cnt, dd, 64);
            if ((tid & 63) == 0) s_redc[tid >> 6] = cnt;
            __syncthreads();
            if (tid == 0) {
                unsigned t = 0;
                for (int w = 0; w < BLOCK / 64; ++w) t += s_redc[w];
                s_total = t;
            }
            __syncthreads();
            unsigned c1 = s_total;
            if (r < c1) prefix |= bitMask; else r -= c1;
            __syncthreads();
        }
        unsigned K1 = prefix;
        unsigned cge = 0, mb = 0;
#pragma unroll
        for (int j = 0; j < VPT; ++j) {
            unsigned ks[4] = {f2k(d[j].x), f2k(d[j].y), f2k(d[j].z), f2k(d[j].w)};
#pragma unroll
            for (int q = 0; q < 4; ++q) {
                unsigned k = ks[q];
                if (k >= K1) cge++; else mb = mb > k ? mb : k;
            }
        }
#pragma unroll
        for (int dd = 32; dd >= 1; dd >>= 1) {
            cge += __shfl_xor(cge, dd, 64);
            unsigned om = __shfl_xor(mb, dd, 64);
            mb = mb > om ? mb : om;
        }
        if ((tid & 63) == 0) { s_redc[tid >> 6] = cge; s_redm[tid >> 6] = mb; }
        __syncthreads();
        if (tid == 0) {
            unsigned t = 0, m = 0;
            for (int w = 0; w < BLOCK / 64; ++w) {
                t += s_redc[w];
                m = m > s_redm[w] ? m : s_redm[w];
            }
            unsigned K2 = (t >= R2 + 1u) ? K1 : m;
            s_v1 = k2f(K1);
            s_v2 = k2f(K2);
        }
    }
    __syncthreads();

    const float thr = (s_v1 + s_v2) * 0.5f;

    // ---- Pass C: mask from registers -> global ----
#pragma unroll
    for (int j = 0; j < VPT; ++j) {
        float4 f = d[j];
        float4 m;
        m.x = (f.x > thr) ? 1.0f : 0.0f;
        m.y = (f.y > thr) ? 1.0f : 0.0f;
        m.z = (f.z > thr) ? 1.0f : 0.0f;
        m.w = (f.w > thr) ? 1.0f : 0.0f;
        o4[j * BLOCK + tid] = m;
    }
}

extern "C" void kernel_launch(void* const* d_in, const int* in_sizes, int n_in,
                              void* d_out, int out_size, void* d_ws, size_t ws_size,
                              hipStream_t stream) {
    const float* x = (const float*)d_in[0];
    float* out = (float*)d_out;
    int batch = in_sizes[0] / DDIM;
    kwta_kernel<<<batch, BLOCK, 0, stream>>>(x, out);
}